// Round 3
// 245.475 us; speedup vs baseline: 1.0092x; 1.0092x over previous
//
#include <hip/hip_runtime.h>
#include <hip/hip_bf16.h>

// Problem constants (GPT-2 style attention block)
#define BB 8
#define SS 1024
#define NXX 1024
#define HH 16
#define DD 64
#define MM (BB * SS)

typedef __attribute__((ext_vector_type(8))) short short8;   // 8 bf16 = 4 VGPRs
typedef __attribute__((ext_vector_type(4))) short short4v;  // 4 bf16 = 8 B
typedef __attribute__((ext_vector_type(4))) float float4v;  // MFMA C/D

static __device__ inline short bf16bits(float v) {
    __hip_bfloat16 t = __float2bfloat16(v);
    return *reinterpret_cast<short*>(&t);
}

// ---------------------------------------------------------------------------
// Prep kernel: one launch does x->bf16 convert + both weight transposes.
//   blocks [0, 8192):        f2b of x (1024 elems/block)
//   blocks [8192, 11264):    w_attn^T  (32x32 tiles, 1024x3072)
//   blocks [11264, 12288):   w_proj^T  (32x32 tiles, 1024x1024)
// ---------------------------------------------------------------------------
__global__ __launch_bounds__(256) void prep_kernel(
    const float* __restrict__ x, __hip_bfloat16* __restrict__ xb,
    const float* __restrict__ w_attn, __hip_bfloat16* __restrict__ wT_attn,
    const float* __restrict__ w_proj, __hip_bfloat16* __restrict__ wT_proj)
{
    __shared__ __hip_bfloat16 tile[32][33];
    const int blk = blockIdx.x;
    const int tid = threadIdx.x;

    if (blk < 8192) {
        int i = blk * 1024 + tid * 4;
        float4 v = *(const float4*)(x + i);
        xb[i + 0] = __float2bfloat16(v.x);
        xb[i + 1] = __float2bfloat16(v.y);
        xb[i + 2] = __float2bfloat16(v.z);
        xb[i + 3] = __float2bfloat16(v.w);
        return;
    }
    const float* W;
    __hip_bfloat16* Wt;
    int K, N, idx;
    if (blk < 8192 + 3072) { idx = blk - 8192;  W = w_attn; Wt = wT_attn; K = NXX; N = 3 * NXX; }
    else                   { idx = blk - 11264; W = w_proj; Wt = wT_proj; K = NXX; N = NXX; }
    const int k0 = (idx % (K / 32)) * 32;
    const int n0 = (idx / (K / 32)) * 32;
    const int tx = tid % 32;
    const int ty = tid / 32;
#pragma unroll
    for (int p = 0; p < 4; ++p) {
        int k = ty + p * 8;
        tile[k][tx] = __float2bfloat16(W[(size_t)(k0 + k) * N + n0 + tx]);
    }
    __syncthreads();
#pragma unroll
    for (int p = 0; p < 4; ++p) {
        int nn = ty + p * 8;
        Wt[(size_t)(n0 + nn) * K + k0 + tx] = tile[tx][nn];
    }
}

// ---------------------------------------------------------------------------
// 256x256 8-wave pipelined bf16 MFMA GEMM, 64 KiB LDS (T1+T2+T4+T5).
//   C = A @ Bt^T + bias. BK=32, double-buffered, 2 phases per K-tile,
//   counted vmcnt(2), XOR swizzle slot^=(row>>1)&3 on 16B slots of 64B rows.
// MODE 0: fp32 C (proj). MODE 1: QKV mode -- bf16 C for Q (x0.125) and K
// columns; V columns (n0>=2048) written transposed to vT[b,h,d,s].
//
// LDS map (64 KiB): buf p at p*32768; A [256 rows][64 B] at +0, B at +16384.
// STAGE2 = 2 x global_load_lds_dwordx4 per thread (512 thr x 16 B = 8 KiB =
// 128 rows per issue).
//
// Per K-tile t (cur = t&1):
//   ph0: ds A[m0-3]+B[all] (8xb128) | stage (t+1).A -> buf[t+1] |
//        bar; lgkm0+schedbar; setprio1; 16 MFMA; setprio0; bar
//   ph1: ds A[m4-7] (4xb128)        | stage (t+2).B -> buf[t].B (dead after
//        ph0's closing bar) | vmcnt(2) | bar; lgkm0; 16 MFMA; bar
// Ledger at ph1 wait: (t+1).B[2] + (t+1).A[2] + (t+2).B[2] = 6 -> vmcnt(2)
// retires tile t+1's data, keeps (t+2).B in flight. Prologue: T0.A,T0.B,T1.B
// then vmcnt(2). Tail t=NT-2: vmcnt(0). Rule #18: sched_barrier(0) after
// every inline lgkmcnt(0).
// ---------------------------------------------------------------------------
#define STAGE2(SRC, DST, kk)                                                   \
    {                                                                          \
        _Pragma("unroll") for (int j_ = 0; j_ < 2; ++j_) {                     \
            const __hip_bfloat16* s_ = (SRC) + (size_t)(j_ * 128) * K + (kk);  \
            char* d_ = (char*)(DST) + j_ * 8192 + (wave << 10);                \
            __builtin_amdgcn_global_load_lds(                                  \
                (const __attribute__((address_space(1))) void*)s_,             \
                (__attribute__((address_space(3))) void*)d_, 16, 0, 0);        \
        }                                                                      \
    }

#define WAIT_LGKM0_FENCED()                                                    \
    asm volatile("s_waitcnt lgkmcnt(0)" ::: "memory");                         \
    __builtin_amdgcn_sched_barrier(0);

template <int MODE>
__global__ __launch_bounds__(512, 2) void gemm256(
    const __hip_bfloat16* __restrict__ A,   // M x K row-major
    const __hip_bfloat16* __restrict__ Bt,  // N x K row-major
    const float* __restrict__ bias,
    void* __restrict__ Cv,                  // M x N
    __hip_bfloat16* __restrict__ vT,        // MODE 1 only
    int M, int K, int N)
{
    __shared__ __attribute__((aligned(16))) char smem[65536];

    const int tid  = threadIdx.x;
    const int wave = tid >> 6;
    const int lane = tid & 63;
    const int wr = wave >> 2;   // 0..1: M half (128 rows/wave)
    const int wc = wave & 3;    // 0..3: N quarter (64 cols/wave)

    // XCD-aware bijective block swizzle (gridDim.x % 8 == 0 for both calls)
    const int nwg = (int)gridDim.x;
    const int cpx = nwg >> 3;
    const int bid = (int)blockIdx.x;
    const int swz = (bid & 7) * cpx + (bid >> 3);
    const int mtiles = M >> 8;
    const int m0 = (swz % mtiles) << 8;
    const int n0 = (swz / mtiles) << 8;

    const int NT = K >> 5;   // 32 K-tiles of BK=32

    // staging source: 4 threads/row, pre-swizzled column (rule #21):
    //   row = j*128 + (tid>>2); slot' = (tid&3); src slot = slot' ^ ((row>>1)&3)
    //   with (row>>1)&3 == (tid>>3)&3 (j*128, wave*16 are multiples of 8).
    const int row_s  = tid >> 2;                              // 0..127
    const int srccol = (((tid & 3) ^ ((tid >> 3) & 3)) << 3); // bf16 elems
    const __hip_bfloat16* aSrc = A  + (size_t)(m0 + row_s) * K + srccol;
    const __hip_bfloat16* bSrc = Bt + (size_t)(n0 + row_s) * K + srccol;

    // fragment reads: row r, 16B slot (q4 ^ ((r>>1)&3)); r>>1&3 == (l15>>1)&3
    const int l15 = lane & 15, q4 = lane >> 4;
    const int skey = (l15 >> 1) & 3;
    const int sslot = (q4 ^ skey) << 4;
    const int offA = ((wr << 7) + l15) * 64 + sslot;           // within A region
    const int offB = 16384 + ((wc << 6) + l15) * 64 + sslot;   // within B region

    float4v acc[8][4];
#pragma unroll
    for (int i = 0; i < 8; ++i)
#pragma unroll
        for (int j = 0; j < 4; ++j) acc[i][j] = (float4v){0.f, 0.f, 0.f, 0.f};

    // prologue: T0.A->buf0.A, T0.B->buf0.B, T1.B->buf1.B; keep T1.B in flight
    STAGE2(aSrc, smem, 0);
    STAGE2(bSrc, smem + 16384, 0);
    if (NT > 1) {
        STAGE2(bSrc, smem + 32768 + 16384, 32);
        asm volatile("s_waitcnt vmcnt(2)" ::: "memory");
    } else {
        asm volatile("s_waitcnt vmcnt(0)" ::: "memory");
    }
    __builtin_amdgcn_s_barrier();

    for (int t = 0; t < NT; ++t) {
        char* bufc = (char*)smem + ((t & 1) << 15);
        char* bufn = (char*)smem + (((t + 1) & 1) << 15);
        const char* Ab = bufc;

        short8 a[8], b[4];

        // ---- phase 0: A[m0-3] + B[all]; stage (t+1).A
#pragma unroll
        for (int mf = 0; mf < 4; ++mf) a[mf] = *(const short8*)(Ab + offA + mf * 1024);
#pragma unroll
        for (int nf = 0; nf < 4; ++nf) b[nf] = *(const short8*)(bufc + offB + nf * 1024);
        if (t + 1 < NT) STAGE2(aSrc, bufn, (t + 1) << 5);
        __builtin_amdgcn_s_barrier();
        WAIT_LGKM0_FENCED();
        __builtin_amdgcn_s_setprio(1);
#pragma unroll
        for (int mf = 0; mf < 4; ++mf)
#pragma unroll
            for (int nf = 0; nf < 4; ++nf)
                acc[mf][nf] = __builtin_amdgcn_mfma_f32_16x16x32_bf16(
                    a[mf], b[nf], acc[mf][nf], 0, 0, 0);
        __builtin_amdgcn_s_setprio(0);
        __builtin_amdgcn_s_barrier();

        // ---- phase 1: A[m4-7]; stage (t+2).B into cur.B; counted vmcnt
#pragma unroll
        for (int mf = 0; mf < 4; ++mf) a[mf + 4] = *(const short8*)(Ab + offA + (mf + 4) * 1024);
        if (t + 2 < NT) {
            STAGE2(bSrc, bufc + 16384, (t + 2) << 5);
            asm volatile("s_waitcnt vmcnt(2)" ::: "memory");  // tile t+1 ready
        } else if (t + 1 < NT) {
            asm volatile("s_waitcnt vmcnt(0)" ::: "memory");  // tail drain
        }
        __builtin_amdgcn_s_barrier();
        WAIT_LGKM0_FENCED();
        __builtin_amdgcn_s_setprio(1);
#pragma unroll
        for (int mf = 0; mf < 4; ++mf)
#pragma unroll
            for (int nf = 0; nf < 4; ++nf)
                acc[mf + 4][nf] = __builtin_amdgcn_mfma_f32_16x16x32_bf16(
                    a[mf + 4], b[nf], acc[mf + 4][nf], 0, 0, 0);
        __builtin_amdgcn_s_setprio(0);
        __builtin_amdgcn_s_barrier();
    }

    // Epilogue. C/D map: col = lane&15, row = (lane>>4)*4 + reg
    const int cr = q4 * 4;
    const int cc = l15;

    if (MODE == 1 && n0 >= 2048) {
        // V columns -> vT[(b*H+h)*64+d][s], 4 consecutive-s regs pack to 8B
        const int bb = m0 / SS;  // 256-row block stays within one batch
#pragma unroll
        for (int mf = 0; mf < 8; ++mf) {
            int grow = m0 + (wr << 7) + mf * 16 + cr;
            int ssr = grow & (SS - 1);
#pragma unroll
            for (int nf = 0; nf < 4; ++nf) {
                int gcol = n0 + (wc << 6) + nf * 16 + cc;
                float bv = bias[gcol];
                int col = gcol - 2048;
                int hh = col >> 6, dd = col & 63;
                short4v pk;
#pragma unroll
                for (int r = 0; r < 4; ++r) pk[r] = bf16bits(acc[mf][nf][r] + bv);
                *(short4v*)(vT + (size_t)((bb * HH + hh) * 64 + dd) * SS + ssr) = pk;
            }
        }
    } else {
        const float qs = (MODE == 1 && n0 < 1024) ? 0.125f : 1.0f;  // fold 1/sqrt(D)
#pragma unroll
        for (int mf = 0; mf < 8; ++mf) {
            int grow = m0 + (wr << 7) + mf * 16 + cr;
#pragma unroll
            for (int nf = 0; nf < 4; ++nf) {
                int gcol = n0 + (wc << 6) + nf * 16 + cc;
                float bv = bias[gcol];
#pragma unroll
                for (int r = 0; r < 4; ++r) {
                    float v = (acc[mf][nf][r] + bv) * qs;
                    if constexpr (MODE == 1)
                        ((__hip_bfloat16*)Cv)[(size_t)(grow + r) * N + gcol] =
                            __float2bfloat16(v);
                    else
                        ((float*)Cv)[(size_t)(grow + r) * N + gcol] = v;
                }
            }
        }
    }
}

// ---------------------------------------------------------------------------
// MFMA causal flash attention, no-max softmax (scores bounded; exp(-1e10)=0).
// Block: (b,h) x 128 queries, 4 waves x (2 x 16q subtiles). 64-key tiles.
// Ks[key][d] from qkv (Q pre-scaled 1/8 upstream), Vs=V^T[d][key] from vT.
// l-reduction deferred to epilogue (no shfls in the loop).
// ---------------------------------------------------------------------------
#define PSTR 72

__global__ __launch_bounds__(256) void attn_mfma_kernel(
    const __hip_bfloat16* __restrict__ qkv,
    const __hip_bfloat16* __restrict__ vT,
    __hip_bfloat16* __restrict__ aout)
{
    const int bh = blockIdx.x;
    const int b = bh / HH, h = bh % HH;
    const int q0 = ((int)gridDim.y - 1 - (int)blockIdx.y) * 128;  // heavy first

    __shared__ __hip_bfloat16 Ks[64 * PSTR];     // [key][d]
    __shared__ __hip_bfloat16 Vs[64 * PSTR];     // V^T: [d][key]
    __shared__ __hip_bfloat16 Ps[4][32 * PSTR];  // per-wave P, [q_local][key]

    const int tid  = threadIdx.x;
    const int wave = tid >> 6;
    const int lane = tid & 63;
    const int quad = lane >> 4;
    const int l16  = lane & 15;

    // Q A-fragments (pre-scaled): A[m=l16][k = kc*32 + quad*8 + j]
    short8 qf[2][2];
#pragma unroll
    for (int t = 0; t < 2; ++t) {
        const __hip_bfloat16* qp = qkv +
            (size_t)(b * SS + q0 + wave * 32 + t * 16 + l16) * 3072 + h * 64 + quad * 8;
        qf[t][0] = *(const short8*)qp;
        qf[t][1] = *(const short8*)(qp + 32);
    }

    float4v o_acc[2][4];
    float l_acc[2][4];
#pragma unroll
    for (int t = 0; t < 2; ++t)
#pragma unroll
        for (int nt = 0; nt < 4; ++nt) o_acc[t][nt] = (float4v){0.f, 0.f, 0.f, 0.f};
#pragma unroll
    for (int t = 0; t < 2; ++t)
#pragma unroll
        for (int r = 0; r < 4; ++r) l_acc[t][r] = 0.f;

    const int sk  = tid & 63;          // K staging: key row
    const int sdo = (tid >> 6) * 16;   // K staging: d offset
    const int vd  = tid >> 2;          // V staging: d row
    const int vko = (tid & 3) * 16;    // V staging: key offset
    const int qmin_w = q0 + wave * 32;
    const int nkt = q0 / 64 + 2;       // keys up to q0+127

    for (int kt = 0; kt < nkt; ++kt) {
        const int k0 = kt * 64;
        __syncthreads();
        {
            const __hip_bfloat16* kr =
                qkv + (size_t)(b * SS + k0 + sk) * 3072 + 1024 + h * 64 + sdo;
            *(short8*)&Ks[sk * PSTR + sdo]     = *(const short8*)kr;
            *(short8*)&Ks[sk * PSTR + sdo + 8] = *(const short8*)(kr + 8);
            const __hip_bfloat16* vr = vT + (size_t)(bh * 64 + vd) * SS + k0 + vko;
            *(short8*)&Vs[vd * PSTR + vko]     = *(const short8*)vr;
            *(short8*)&Vs[vd * PSTR + vko + 8] = *(const short8*)(vr + 8);
        }
        __syncthreads();
        if (k0 > qmin_w + 31) continue;  // tile entirely above this wave's diagonal

        // S = Q K^T : 32 queries x 64 keys per wave
        const short* ks = (const short*)Ks;
        float4v sacc[2][4];
#pragma unroll
        for (int t = 0; t < 2; ++t)
#pragma unroll
            for (int nt = 0; nt < 4; ++nt) sacc[t][nt] = (float4v){0.f, 0.f, 0.f, 0.f};
#pragma unroll
        for (int kc = 0; kc < 2; ++kc)
#pragma unroll
            for (int nt = 0; nt < 4; ++nt) {
                short8 kb = *(const short8*)(ks + (nt * 16 + l16) * PSTR + kc * 32 + quad * 8);
                sacc[0][nt] = __builtin_amdgcn_mfma_f32_16x16x32_bf16(qf[0][kc], kb, sacc[0][nt], 0, 0, 0);
                sacc[1][nt] = __builtin_amdgcn_mfma_f32_16x16x32_bf16(qf[1][kc], kb, sacc[1][nt], 0, 0, 0);
            }

        const bool needmask = (k0 + 63 > qmin_w);
        __hip_bfloat16* pw = Ps[wave];
#pragma unroll
        for (int t = 0; t < 2; ++t)
#pragma unroll
            for (int nt = 0; nt < 4; ++nt) {
                int kk = k0 + nt * 16 + l16;
#pragma unroll
                for (int r = 0; r < 4; ++r) {
                    float s = sacc[t][nt][r];
                    if (needmask) {
                        int qq = qmin_w + t * 16 + quad * 4 + r;
                        if (kk > qq) s = -1e10f;
                    }
                    float p = __expf(s);      // no max-shift: s bounded ~|3|
                    l_acc[t][r] += p;         // deferred 16-lane reduction
                    pw[(t * 16 + quad * 4 + r) * PSTR + nt * 16 + l16] =
                        __float2bfloat16(p);
                }
            }

        // O += P V  (intra-wave LDS round-trip; no barrier needed)
        const short* ps = (const short*)pw;
        const short* vs = (const short*)Vs;
#pragma unroll
        for (int kc = 0; kc < 2; ++kc) {
            short8 pa0 = *(const short8*)(ps + (0 * 16 + l16) * PSTR + kc * 32 + quad * 8);
            short8 pa1 = *(const short8*)(ps + (1 * 16 + l16) * PSTR + kc * 32 + quad * 8);
#pragma unroll
            for (int nt = 0; nt < 4; ++nt) {
                short8 vb = *(const short8*)(vs + (nt * 16 + l16) * PSTR + kc * 32 + quad * 8);
                o_acc[0][nt] = __builtin_amdgcn_mfma_f32_16x16x32_bf16(pa0, vb, o_acc[0][nt], 0, 0, 0);
                o_acc[1][nt] = __builtin_amdgcn_mfma_f32_16x16x32_bf16(pa1, vb, o_acc[1][nt], 0, 0, 0);
            }
        }
    }

    // epilogue: reduce l across the 16-lane column groups, write O/l
#pragma unroll
    for (int t = 0; t < 2; ++t)
#pragma unroll
        for (int r = 0; r < 4; ++r) {
            float l = l_acc[t][r];
            l += __shfl_xor(l, 1);
            l += __shfl_xor(l, 2);
            l += __shfl_xor(l, 4);
            l += __shfl_xor(l, 8);
            float inv = 1.f / l;
            int row = q0 + wave * 32 + t * 16 + quad * 4 + r;
            __hip_bfloat16* op = aout + (size_t)(b * SS + row) * NXX + h * 64 + l16;
#pragma unroll
            for (int nt = 0; nt < 4; ++nt)
                op[nt * 16] = __float2bfloat16(o_acc[t][nt][r] * inv);
        }
}

// ---------------------------------------------------------------------------
// Workspace (88 MB):
//   [0, 48M)    qkv bf16 (Q scaled 1/8, K; V region unused)
//   [48, 64M)   vT bf16 [b,h,d,s]
//   [64, 80M)   xb bf16 -- reused as amid after QKV GEMM
//   [80, 86M)   wT_attn bf16
//   [86, 88M)   wT_proj bf16
// ---------------------------------------------------------------------------
extern "C" void kernel_launch(void* const* d_in, const int* in_sizes, int n_in,
                              void* d_out, int out_size, void* d_ws, size_t ws_size,
                              hipStream_t stream)
{
    const float* x      = (const float*)d_in[0];
    const float* w_attn = (const float*)d_in[1];
    const float* b_attn = (const float*)d_in[2];
    const float* w_proj = (const float*)d_in[3];
    const float* b_proj = (const float*)d_in[4];
    float* out = (float*)d_out;

    char* ws = (char*)d_ws;
    __hip_bfloat16* qkv     = (__hip_bfloat16*)ws;
    __hip_bfloat16* vT      = (__hip_bfloat16*)(ws + (size_t)48 * 1024 * 1024);
    __hip_bfloat16* xb      = (__hip_bfloat16*)(ws + (size_t)64 * 1024 * 1024);
    __hip_bfloat16* amid    = xb;
    __hip_bfloat16* wT_attn = (__hip_bfloat16*)(ws + (size_t)80 * 1024 * 1024);
    __hip_bfloat16* wT_proj = (__hip_bfloat16*)(ws + (size_t)86 * 1024 * 1024);

    prep_kernel<<<dim3(12288), dim3(256), 0, stream>>>(
        x, xb, w_attn, wT_attn, w_proj, wT_proj);

    // QKV: 32 x 12 = 384 blocks (divisible by 8 XCDs)
    gemm256<1><<<dim3((MM / 256) * ((3 * NXX) / 256)), dim3(512), 0, stream>>>(
        xb, wT_attn, b_attn, qkv, vT, MM, NXX, 3 * NXX);

    attn_mfma_kernel<<<dim3(BB * HH, SS / 128), dim3(256), 0, stream>>>(qkv, vT, amid);

    // proj: 32 x 4 = 128 blocks
    gemm256<0><<<dim3((MM / 256) * (NXX / 256)), dim3(512), 0, stream>>>(
        amid, wT_proj, b_proj, out, nullptr, MM, NXX, NXX);
}

// Round 4
// 215.492 us; speedup vs baseline: 1.1496x; 1.1391x over previous
//
#include <hip/hip_runtime.h>
#include <hip/hip_bf16.h>

// Problem constants (GPT-2 style attention block)
#define BB 8
#define SS 1024
#define NXX 1024
#define HH 16
#define DD 64
#define MM (BB * SS)

typedef __attribute__((ext_vector_type(8))) short short8;   // 8 bf16 = 4 VGPRs
typedef __attribute__((ext_vector_type(4))) short short4v;  // 4 bf16 = 8 B
typedef __attribute__((ext_vector_type(4))) float float4v;  // MFMA C/D

static __device__ inline short bf16bits(float v) {
    __hip_bfloat16 t = __float2bfloat16(v);
    return *reinterpret_cast<short*>(&t);
}

// ---------------------------------------------------------------------------
// Prep kernel: one launch does x->bf16 convert + both weight transposes.
//   blocks [0, 8192):        f2b of x (1024 elems/block)
//   blocks [8192, 11264):    w_attn^T  (32x32 tiles, 1024x3072)
//   blocks [11264, 12288):   w_proj^T  (32x32 tiles, 1024x1024)
// ---------------------------------------------------------------------------
__global__ __launch_bounds__(256) void prep_kernel(
    const float* __restrict__ x, __hip_bfloat16* __restrict__ xb,
    const float* __restrict__ w_attn, __hip_bfloat16* __restrict__ wT_attn,
    const float* __restrict__ w_proj, __hip_bfloat16* __restrict__ wT_proj)
{
    __shared__ __hip_bfloat16 tile[32][33];
    const int blk = blockIdx.x;
    const int tid = threadIdx.x;

    if (blk < 8192) {
        int i = blk * 1024 + tid * 4;
        float4 v = *(const float4*)(x + i);
        xb[i + 0] = __float2bfloat16(v.x);
        xb[i + 1] = __float2bfloat16(v.y);
        xb[i + 2] = __float2bfloat16(v.z);
        xb[i + 3] = __float2bfloat16(v.w);
        return;
    }
    const float* W;
    __hip_bfloat16* Wt;
    int K, N, idx;
    if (blk < 8192 + 3072) { idx = blk - 8192;  W = w_attn; Wt = wT_attn; K = NXX; N = 3 * NXX; }
    else                   { idx = blk - 11264; W = w_proj; Wt = wT_proj; K = NXX; N = NXX; }
    const int k0 = (idx % (K / 32)) * 32;
    const int n0 = (idx / (K / 32)) * 32;
    const int tx = tid % 32;
    const int ty = tid / 32;
#pragma unroll
    for (int p = 0; p < 4; ++p) {
        int k = ty + p * 8;
        tile[k][tx] = __float2bfloat16(W[(size_t)(k0 + k) * N + n0 + tx]);
    }
    __syncthreads();
#pragma unroll
    for (int p = 0; p < 4; ++p) {
        int nn = ty + p * 8;
        Wt[(size_t)(n0 + nn) * K + k0 + tx] = tile[tx][nn];
    }
}

// ---------------------------------------------------------------------------
// 256x128 8-wave deep-pipelined bf16 MFMA GEMM, 64 KiB LDS.
//   C = A @ Bt^T + bias.  BK=32; A TRIPLE-buffered (3x16K), B DOUBLE-buffered
//   (2x8K); both operands staged at prefetch depth 2 (one full K-tile of
//   slack before the counted vmcnt(3) wait). XOR swizzle slot^=(row>>1)&3 on
//   16B slots of 64B rows (bank-conflict-free, verified round 3: 0 conflicts).
// MODE 0: fp32 C (proj). MODE 1: QKV mode -- bf16 C for Q (x0.125) and K
// columns; V columns (n0>=2048) written transposed to vT[b,h,d,s].
//
// LDS map (64 KiB): A[0]@0, A[1]@16384, A[2]@32768, B[0]@49152, B[1]@57344.
//
// Per K-tile t (Ab=A[t%3], Bb=B[t&1], 2 phases):
//   ph0: ds a[0..1](mf0-1) + b[0..3] (6xb128) | STAGE_A(t+2)->A[(t+2)%3]
//        (region held t-1, reads done) | bar; lgkm0+schedbar; prio1;
//        8 MFMA (mf0-1 x nf0-3); prio0; bar
//   ph1: ds a[2..3] (2xb128) | STAGE_B(t+2)->B[t&1] (B-reads of tile t all
//        done at ph0's closing bar) | vmcnt(3) | bar; lgkm0; 8 MFMA; bar
// Ledger at ph1 wait: A(t+1)[2]@t-1ph0, B(t+1)[1]@t-1ph1, A(t+2)[2]@t-ph0,
// B(t+2)[1]@t-ph1 = 6 outstanding -> vmcnt(3) retires tile t+1's loads
// (issued ONE FULL K-TILE earlier -> HBM latency covered), keeps t+2 in
// flight. Tail: t=NT-2 -> vmcnt(0). Rule #18: sched_barrier(0) after every
// inline lgkmcnt(0).
//
// Grid: grouped-M order (GM=8, N-fastest) under the XCD swizzle -> each XCD
// chunk is an 8M x (cpx/8)N rectangle (A 4MB + B <=3MB working set ~ L2).
// ---------------------------------------------------------------------------
#define STAGE_A(DST, kk)                                                       \
    {                                                                          \
        _Pragma("unroll") for (int j_ = 0; j_ < 2; ++j_) {                     \
            const __hip_bfloat16* s_ = aSrc + (size_t)(j_ * 128) * K + (kk);   \
            char* d_ = (char*)(DST) + j_ * 8192 + (wave << 10);                \
            __builtin_amdgcn_global_load_lds(                                  \
                (const __attribute__((address_space(1))) void*)s_,             \
                (__attribute__((address_space(3))) void*)d_, 16, 0, 0);        \
        }                                                                      \
    }

#define STAGE_B(DST, kk)                                                       \
    {                                                                          \
        const __hip_bfloat16* s_ = bSrc + (kk);                                \
        char* d_ = (char*)(DST) + (wave << 10);                                \
        __builtin_amdgcn_global_load_lds(                                      \
            (const __attribute__((address_space(1))) void*)s_,                 \
            (__attribute__((address_space(3))) void*)d_, 16, 0, 0);            \
    }

#define WAIT_LGKM0_FENCED()                                                    \
    asm volatile("s_waitcnt lgkmcnt(0)" ::: "memory");                         \
    __builtin_amdgcn_sched_barrier(0);

template <int MODE>
__global__ __launch_bounds__(512, 2) void gemm256(
    const __hip_bfloat16* __restrict__ A,   // M x K row-major
    const __hip_bfloat16* __restrict__ Bt,  // N x K row-major
    const float* __restrict__ bias,
    void* __restrict__ Cv,                  // M x N
    __hip_bfloat16* __restrict__ vT,        // MODE 1 only
    int M, int K, int N)
{
    __shared__ __attribute__((aligned(16))) char smem[65536];

    const int tid  = threadIdx.x;
    const int wave = tid >> 6;
    const int lane = tid & 63;
    const int wm = (wave >> 1) << 6;   // 0/64/128/192: M quarter (64 rows)
    const int wn = (wave & 1) << 6;    // 0/64: N half (64 cols)

    // XCD-aware bijective swizzle + grouped-M (GM=8) tile order for L2.
    const int nwg = (int)gridDim.x;
    const int cpx = nwg >> 3;
    const int bid = (int)blockIdx.x;
    const int swz = (bid & 7) * cpx + (bid >> 3);
    const int ntN = N >> 7;            // N/128 tiles
    const int width = ntN << 3;        // GM=8 rows per group
    const int group = swz / width;
    const int w = swz % width;
    const int m0 = ((group << 3) + (w & 7)) << 8;
    const int n0 = (w >> 3) << 7;

    const int NT = K >> 5;   // K-tiles of BK=32 (32 here)

    // staging: 4 threads/row, pre-swizzled source column (rule #21):
    //   LDS row = tid>>2 (+128 for A's 2nd load), slot' = tid&3;
    //   source slot = slot' ^ ((row>>1)&3) = (tid&3) ^ ((tid>>3)&3).
    const int row_s  = tid >> 2;
    const int srccol = (((tid & 3) ^ ((tid >> 3) & 3)) << 3);
    const __hip_bfloat16* aSrc = A  + (size_t)(m0 + row_s) * K + srccol;
    const __hip_bfloat16* bSrc = Bt + (size_t)(n0 + row_s) * K + srccol;

    // fragment reads: row r, 16B slot (q4 ^ ((r>>1)&3)); (r>>1)&3 == (l15>>1)&3
    const int l15 = lane & 15, q4 = lane >> 4;
    const int sslot = (q4 ^ ((l15 >> 1) & 3)) << 4;
    const int offA = (wm + l15) * 64 + sslot;
    const int offB = (wn + l15) * 64 + sslot;

    float4v acc[4][4];
#pragma unroll
    for (int i = 0; i < 4; ++i)
#pragma unroll
        for (int j = 0; j < 4; ++j) acc[i][j] = (float4v){0.f, 0.f, 0.f, 0.f};

    char* const Abuf0 = (char*)smem;
    char* const Bbuf0 = (char*)smem + 49152;

    // prologue: tiles 0 and 1 for both operands; keep tile 1 in flight.
    STAGE_A(Abuf0,          0);   // A[0]
    STAGE_B(Bbuf0,          0);   // B[0]
    STAGE_A(Abuf0 + 16384, 32);   // A[1]
    STAGE_B(Bbuf0 +  8192, 32);   // B[1]
    asm volatile("s_waitcnt vmcnt(3)" ::: "memory");
    __builtin_amdgcn_s_barrier();

    int ia = 0;  // A buffer index of tile t (t % 3)
    for (int t = 0; t < NT; ++t) {
        const char* Ab = Abuf0 + ia * 16384;
        char* Bb = Bbuf0 + ((t & 1) << 13);
        const int ia2 = (ia == 0) ? 2 : ia - 1;   // (t+2) % 3

        short8 a[4], b[4];

        // ---- phase 0: a[0..1] + b[0..3]; stage A(t+2)
#pragma unroll
        for (int mf = 0; mf < 2; ++mf) a[mf] = *(const short8*)(Ab + offA + mf * 1024);
#pragma unroll
        for (int nf = 0; nf < 4; ++nf) b[nf] = *(const short8*)(Bb + offB + nf * 1024);
        if (t + 2 < NT) STAGE_A(Abuf0 + ia2 * 16384, (t + 2) << 5);
        __builtin_amdgcn_s_barrier();
        WAIT_LGKM0_FENCED();
        __builtin_amdgcn_s_setprio(1);
#pragma unroll
        for (int mf = 0; mf < 2; ++mf)
#pragma unroll
            for (int nf = 0; nf < 4; ++nf)
                acc[mf][nf] = __builtin_amdgcn_mfma_f32_16x16x32_bf16(
                    a[mf], b[nf], acc[mf][nf], 0, 0, 0);
        __builtin_amdgcn_s_setprio(0);
        __builtin_amdgcn_s_barrier();

        // ---- phase 1: a[2..3]; stage B(t+2) into B[t&1]; counted vmcnt
#pragma unroll
        for (int mf = 2; mf < 4; ++mf) a[mf] = *(const short8*)(Ab + offA + mf * 1024);
        if (t + 2 < NT) {
            STAGE_B(Bb, (t + 2) << 5);
            asm volatile("s_waitcnt vmcnt(3)" ::: "memory");  // tile t+1 ready
        } else if (t + 1 < NT) {
            asm volatile("s_waitcnt vmcnt(0)" ::: "memory");  // tail drain
        }
        __builtin_amdgcn_s_barrier();
        WAIT_LGKM0_FENCED();
        __builtin_amdgcn_s_setprio(1);
#pragma unroll
        for (int mf = 2; mf < 4; ++mf)
#pragma unroll
            for (int nf = 0; nf < 4; ++nf)
                acc[mf][nf] = __builtin_amdgcn_mfma_f32_16x16x32_bf16(
                    a[mf], b[nf], acc[mf][nf], 0, 0, 0);
        __builtin_amdgcn_s_setprio(0);
        __builtin_amdgcn_s_barrier();

        ia = (ia == 2) ? 0 : ia + 1;
    }

    // Epilogue. C/D map: col = lane&15, row = (lane>>4)*4 + reg
    const int cr = q4 * 4;
    const int cc = l15;

    if (MODE == 1 && n0 >= 2048) {
        // V columns -> vT[(b*H+h)*64+d][s], 4 consecutive-s regs pack to 8B
        const int bb = m0 / SS;  // 256-row block stays within one batch
#pragma unroll
        for (int mf = 0; mf < 4; ++mf) {
            int grow = m0 + wm + mf * 16 + cr;
            int ssr = grow & (SS - 1);
#pragma unroll
            for (int nf = 0; nf < 4; ++nf) {
                int gcol = n0 + wn + nf * 16 + cc;
                float bv = bias[gcol];
                int col = gcol - 2048;
                int hh = col >> 6, dd = col & 63;
                short4v pk;
#pragma unroll
                for (int r = 0; r < 4; ++r) pk[r] = bf16bits(acc[mf][nf][r] + bv);
                *(short4v*)(vT + (size_t)((bb * HH + hh) * 64 + dd) * SS + ssr) = pk;
            }
        }
    } else {
        const float qs = (MODE == 1 && n0 < 1024) ? 0.125f : 1.0f;  // fold 1/sqrt(D)
#pragma unroll
        for (int mf = 0; mf < 4; ++mf) {
            int grow = m0 + wm + mf * 16 + cr;
#pragma unroll
            for (int nf = 0; nf < 4; ++nf) {
                int gcol = n0 + wn + nf * 16 + cc;
                float bv = bias[gcol];
#pragma unroll
                for (int r = 0; r < 4; ++r) {
                    float v = (acc[mf][nf][r] + bv) * qs;
                    if constexpr (MODE == 1)
                        ((__hip_bfloat16*)Cv)[(size_t)(grow + r) * N + gcol] =
                            __float2bfloat16(v);
                    else
                        ((float*)Cv)[(size_t)(grow + r) * N + gcol] = v;
                }
            }
        }
    }
}

// ---------------------------------------------------------------------------
// MFMA causal flash attention, no-max softmax (scores bounded; exp(-1e10)=0).
// Block: (b,h) x 128 queries, 4 waves x (2 x 16q subtiles). 64-key tiles.
// Ks[key][d] from qkv (Q pre-scaled 1/8 upstream), Vs=V^T[d][key] from vT.
// l-reduction deferred to epilogue (no shfls in the loop).
// ---------------------------------------------------------------------------
#define PSTR 72

__global__ __launch_bounds__(256) void attn_mfma_kernel(
    const __hip_bfloat16* __restrict__ qkv,
    const __hip_bfloat16* __restrict__ vT,
    __hip_bfloat16* __restrict__ aout)
{
    const int bh = blockIdx.x;
    const int b = bh / HH, h = bh % HH;
    const int q0 = ((int)gridDim.y - 1 - (int)blockIdx.y) * 128;  // heavy first

    __shared__ __hip_bfloat16 Ks[64 * PSTR];     // [key][d]
    __shared__ __hip_bfloat16 Vs[64 * PSTR];     // V^T: [d][key]
    __shared__ __hip_bfloat16 Ps[4][32 * PSTR];  // per-wave P, [q_local][key]

    const int tid  = threadIdx.x;
    const int wave = tid >> 6;
    const int lane = tid & 63;
    const int quad = lane >> 4;
    const int l16  = lane & 15;

    // Q A-fragments (pre-scaled): A[m=l16][k = kc*32 + quad*8 + j]
    short8 qf[2][2];
#pragma unroll
    for (int t = 0; t < 2; ++t) {
        const __hip_bfloat16* qp = qkv +
            (size_t)(b * SS + q0 + wave * 32 + t * 16 + l16) * 3072 + h * 64 + quad * 8;
        qf[t][0] = *(const short8*)qp;
        qf[t][1] = *(const short8*)(qp + 32);
    }

    float4v o_acc[2][4];
    float l_acc[2][4];
#pragma unroll
    for (int t = 0; t < 2; ++t)
#pragma unroll
        for (int nt = 0; nt < 4; ++nt) o_acc[t][nt] = (float4v){0.f, 0.f, 0.f, 0.f};
#pragma unroll
    for (int t = 0; t < 2; ++t)
#pragma unroll
        for (int r = 0; r < 4; ++r) l_acc[t][r] = 0.f;

    const int sk  = tid & 63;          // K staging: key row
    const int sdo = (tid >> 6) * 16;   // K staging: d offset
    const int vd  = tid >> 2;          // V staging: d row
    const int vko = (tid & 3) * 16;    // V staging: key offset
    const int qmin_w = q0 + wave * 32;
    const int nkt = q0 / 64 + 2;       // keys up to q0+127

    for (int kt = 0; kt < nkt; ++kt) {
        const int k0 = kt * 64;
        __syncthreads();
        {
            const __hip_bfloat16* kr =
                qkv + (size_t)(b * SS + k0 + sk) * 3072 + 1024 + h * 64 + sdo;
            *(short8*)&Ks[sk * PSTR + sdo]     = *(const short8*)kr;
            *(short8*)&Ks[sk * PSTR + sdo + 8] = *(const short8*)(kr + 8);
            const __hip_bfloat16* vr = vT + (size_t)(bh * 64 + vd) * SS + k0 + vko;
            *(short8*)&Vs[vd * PSTR + vko]     = *(const short8*)vr;
            *(short8*)&Vs[vd * PSTR + vko + 8] = *(const short8*)(vr + 8);
        }
        __syncthreads();
        if (k0 > qmin_w + 31) continue;  // tile entirely above this wave's diagonal

        // S = Q K^T : 32 queries x 64 keys per wave
        const short* ks = (const short*)Ks;
        float4v sacc[2][4];
#pragma unroll
        for (int t = 0; t < 2; ++t)
#pragma unroll
            for (int nt = 0; nt < 4; ++nt) sacc[t][nt] = (float4v){0.f, 0.f, 0.f, 0.f};
#pragma unroll
        for (int kc = 0; kc < 2; ++kc)
#pragma unroll
            for (int nt = 0; nt < 4; ++nt) {
                short8 kb = *(const short8*)(ks + (nt * 16 + l16) * PSTR + kc * 32 + quad * 8);
                sacc[0][nt] = __builtin_amdgcn_mfma_f32_16x16x32_bf16(qf[0][kc], kb, sacc[0][nt], 0, 0, 0);
                sacc[1][nt] = __builtin_amdgcn_mfma_f32_16x16x32_bf16(qf[1][kc], kb, sacc[1][nt], 0, 0, 0);
            }

        const bool needmask = (k0 + 63 > qmin_w);
        __hip_bfloat16* pw = Ps[wave];
#pragma unroll
        for (int t = 0; t < 2; ++t)
#pragma unroll
            for (int nt = 0; nt < 4; ++nt) {
                int kk = k0 + nt * 16 + l16;
#pragma unroll
                for (int r = 0; r < 4; ++r) {
                    float s = sacc[t][nt][r];
                    if (needmask) {
                        int qq = qmin_w + t * 16 + quad * 4 + r;
                        if (kk > qq) s = -1e10f;
                    }
                    float p = __expf(s);      // no max-shift: s bounded ~|3|
                    l_acc[t][r] += p;         // deferred 16-lane reduction
                    pw[(t * 16 + quad * 4 + r) * PSTR + nt * 16 + l16] =
                        __float2bfloat16(p);
                }
            }

        // O += P V  (intra-wave LDS round-trip; no barrier needed)
        const short* ps = (const short*)pw;
        const short* vs = (const short*)Vs;
#pragma unroll
        for (int kc = 0; kc < 2; ++kc) {
            short8 pa0 = *(const short8*)(ps + (0 * 16 + l16) * PSTR + kc * 32 + quad * 8);
            short8 pa1 = *(const short8*)(ps + (1 * 16 + l16) * PSTR + kc * 32 + quad * 8);
#pragma unroll
            for (int nt = 0; nt < 4; ++nt) {
                short8 vb = *(const short8*)(vs + (nt * 16 + l16) * PSTR + kc * 32 + quad * 8);
                o_acc[0][nt] = __builtin_amdgcn_mfma_f32_16x16x32_bf16(pa0, vb, o_acc[0][nt], 0, 0, 0);
                o_acc[1][nt] = __builtin_amdgcn_mfma_f32_16x16x32_bf16(pa1, vb, o_acc[1][nt], 0, 0, 0);
            }
        }
    }

    // epilogue: reduce l across the 16-lane column groups, write O/l
#pragma unroll
    for (int t = 0; t < 2; ++t)
#pragma unroll
        for (int r = 0; r < 4; ++r) {
            float l = l_acc[t][r];
            l += __shfl_xor(l, 1);
            l += __shfl_xor(l, 2);
            l += __shfl_xor(l, 4);
            l += __shfl_xor(l, 8);
            float inv = 1.f / l;
            int row = q0 + wave * 32 + t * 16 + quad * 4 + r;
            __hip_bfloat16* op = aout + (size_t)(b * SS + row) * NXX + h * 64 + l16;
#pragma unroll
            for (int nt = 0; nt < 4; ++nt)
                op[nt * 16] = __float2bfloat16(o_acc[t][nt][r] * inv);
        }
}

// ---------------------------------------------------------------------------
// Workspace (88 MB):
//   [0, 48M)    qkv bf16 (Q scaled 1/8, K; V region unused)
//   [48, 64M)   vT bf16 [b,h,d,s]
//   [64, 80M)   xb bf16 -- reused as amid after QKV GEMM
//   [80, 86M)   wT_attn bf16
//   [86, 88M)   wT_proj bf16
// ---------------------------------------------------------------------------
extern "C" void kernel_launch(void* const* d_in, const int* in_sizes, int n_in,
                              void* d_out, int out_size, void* d_ws, size_t ws_size,
                              hipStream_t stream)
{
    const float* x      = (const float*)d_in[0];
    const float* w_attn = (const float*)d_in[1];
    const float* b_attn = (const float*)d_in[2];
    const float* w_proj = (const float*)d_in[3];
    const float* b_proj = (const float*)d_in[4];
    float* out = (float*)d_out;

    char* ws = (char*)d_ws;
    __hip_bfloat16* qkv     = (__hip_bfloat16*)ws;
    __hip_bfloat16* vT      = (__hip_bfloat16*)(ws + (size_t)48 * 1024 * 1024);
    __hip_bfloat16* xb      = (__hip_bfloat16*)(ws + (size_t)64 * 1024 * 1024);
    __hip_bfloat16* amid    = xb;
    __hip_bfloat16* wT_attn = (__hip_bfloat16*)(ws + (size_t)80 * 1024 * 1024);
    __hip_bfloat16* wT_proj = (__hip_bfloat16*)(ws + (size_t)86 * 1024 * 1024);

    prep_kernel<<<dim3(12288), dim3(256), 0, stream>>>(
        x, xb, w_attn, wT_attn, w_proj, wT_proj);

    // QKV: 32 x 24 = 768 blocks (3 even rounds of 256 CUs)
    gemm256<1><<<dim3((MM / 256) * ((3 * NXX) / 128)), dim3(512), 0, stream>>>(
        xb, wT_attn, b_attn, qkv, vT, MM, NXX, 3 * NXX);

    attn_mfma_kernel<<<dim3(BB * HH, SS / 128), dim3(256), 0, stream>>>(qkv, vT, amid);

    // proj: 32 x 8 = 256 blocks (1 even round)
    gemm256<0><<<dim3((MM / 256) * (NXX / 128)), dim3(512), 0, stream>>>(
        amid, wT_proj, b_proj, out, nullptr, MM, NXX, NXX);
}